// Round 16
// baseline (104.703 us; speedup 1.0000x reference)
//
#include <hip/hip_runtime.h>
#include <hip/hip_bf16.h>

#define NN 20000
#define EE 160000
#define HH 32
#define MIDD 32
#define NB 64
#define EPB 2500   // EE / NB exactly

typedef _Float16 f16x4 __attribute__((ext_vector_type(4)));
typedef _Float16 f16x8 __attribute__((ext_vector_type(8)));
typedef float f32x4 __attribute__((ext_vector_type(4)));

__device__ __forceinline__ float silu_f(float v) {
    return __fdividef(v, 1.0f + __expf(-v));
}

// async global->LDS, 4B per lane; LDS dest = wave-uniform base + 4*lane.
__device__ __forceinline__ void gload_lds_b32(const void* gsrc, void* ldst) {
    __builtin_amdgcn_global_load_lds(
        (const __attribute__((address_space(1))) void*)gsrc,
        (__attribute__((address_space(3))) void*)ldst, 4, 0, 0);
}

// pair-slot XOR key for 64B rows.
__device__ __forceinline__ int swz4(int e) { return ((e >> 2) & 3) << 2; }

// ---------------- prep: per-block LDS histogram + Wt build + x16 + flag=0 --
__global__ __launch_bounds__(256) void prep_kernel(
    const int* __restrict__ ei,
    const float* __restrict__ w2a, const float* __restrict__ b2a,
    const float* __restrict__ ra,
    const float* __restrict__ w2b, const float* __restrict__ b2b,
    const float* __restrict__ rb,
    const float* __restrict__ x,
    unsigned int* __restrict__ histG,
    _Float16* __restrict__ Wt1, _Float16* __restrict__ Wt2,
    _Float16* __restrict__ x16, int* __restrict__ flag) {
    const int t = threadIdx.x;
    if (blockIdx.x < NB) {
        __shared__ unsigned int h2[NN / 2];
        for (int i = t; i < NN / 2; i += 256) h2[i] = 0u;
        __syncthreads();
        const int base = blockIdx.x * EPB;
        for (int e = base + t; e < base + EPB; e += 256) {
            int d = ei[EE + e];
            atomicAdd(&h2[d >> 1], 1u << ((d & 1) * 16));
        }
        __syncthreads();
        unsigned int* outp = histG + (size_t)blockIdx.x * NN;
        for (int n = t; n < NN; n += 256)
            outp[n] = (h2[n >> 1] >> ((n & 1) * 16)) & 0xFFFFu;
        return;
    }
    if (blockIdx.x == NB && t == 0) *flag = 0;
    int idx = (blockIdx.x - NB) * 256 + t;
    if (idx < 17408) {                       // 32 * 544 (CIN=16)
        int o = idx / 544, k = idx % 544;
        float v;
        if (k < 512) {
            int m = k & 31, i = k >> 5;
            v = w2a[m * 512 + i * 32 + o];
        } else if (k < 528) {
            v = b2a[(k - 512) * 32 + o];
        } else {
            v = ra[(k - 528) * 32 + o];
        }
        Wt1[o * 544 + k] = (_Float16)v;
    } else if (idx < 52224) {                // + 32 * 1088 (CIN=32)
        int j = idx - 17408;
        int o = j / 1088, k = j % 1088;
        float v;
        if (k < 1024) {
            int m = k & 31, i = k >> 5;
            v = w2b[m * 1024 + i * 32 + o];
        } else if (k < 1056) {
            v = b2b[(k - 1024) * 32 + o];
        } else {
            v = rb[(k - 1056) * 32 + o];
        }
        Wt2[o * 1088 + k] = (_Float16)v;
    } else if (idx < 52224 + NN * 16) {      // x -> fp16
        int j = idx - 52224;
        x16[j] = (_Float16)x[j];
    }
}

// colscan + (last block) full scan — ticket pattern verified in round 14.
__global__ __launch_bounds__(256) void colscan_scan_kernel(
    unsigned int* __restrict__ histG, int* __restrict__ cnt,
    float* __restrict__ invc, int* __restrict__ off, int* __restrict__ flag) {
    const int n = blockIdx.x * 256 + threadIdx.x;
    if (n < NN) {
        unsigned int s = 0;
        #pragma unroll 4
        for (int b = 0; b < NB; ++b) {
            unsigned int v = histG[(size_t)b * NN + n];
            histG[(size_t)b * NN + n] = s;
            s += v;
        }
        cnt[n] = (int)s;
        invc[n] = 1.0f / fmaxf((float)s, 1.0f);
    }
    __threadfence();
    __shared__ int isLast;
    __shared__ int wtot[4];
    if (threadIdx.x == 0)
        isLast = (atomicAdd(flag, 1) == (int)gridDim.x - 1) ? 1 : 0;
    __syncthreads();
    if (!isLast) return;

    // ---- final scan: 256 threads, 80 elements each (250 active) ----
    const int t = threadIdx.x;
    const int base = t * 80;
    int s = 0;
    if (base + 80 <= NN) {
        #pragma unroll
        for (int q = 0; q < 20; ++q) {
            int4 v = ((const int4*)(cnt + base))[q];
            s += v.x + v.y + v.z + v.w;
        }
    }
    const int lane = t & 63, wv = t >> 6;
    int incl = s;
    #pragma unroll
    for (int d2 = 1; d2 < 64; d2 <<= 1) {
        int u = __shfl_up(incl, d2);
        if (lane >= d2) incl += u;
    }
    if (lane == 63) wtot[wv] = incl;
    __syncthreads();
    int wbase = 0;
    for (int p2 = 0; p2 < wv; ++p2) wbase += wtot[p2];
    int running = wbase + incl - s;          // exclusive prefix
    if (base + 80 <= NN) {
        #pragma unroll
        for (int q = 0; q < 20; ++q) {
            int4 v = ((const int4*)(cnt + base))[q];
            int4 o;
            o.x = running;
            o.y = running + v.x;
            o.z = o.y + v.y;
            o.w = o.z + v.z;
            ((int4*)(off + base))[q] = o;
            running = o.w + v.w;
        }
    }
    if (t == 0) off[NN] = EE;
}

// scatter without global atomics (round-13 verified).
__global__ __launch_bounds__(256) void scatter2_kernel(
    const int* __restrict__ ei, const float* __restrict__ ewt,
    const int* __restrict__ off, const unsigned int* __restrict__ histG,
    int2* __restrict__ spair) {
    __shared__ unsigned int r2[NN / 2];
    const int t = threadIdx.x, b = blockIdx.x;
    for (int i = t; i < NN / 2; i += 256) r2[i] = 0u;
    __syncthreads();
    const int base = b * EPB;
    const unsigned int* hb = histG + (size_t)b * NN;
    for (int e = base + t; e < base + EPB; e += 256) {
        int d = ei[EE + e];
        unsigned int old = atomicAdd(&r2[d >> 1], 1u << ((d & 1) * 16));
        int rank = (int)((old >> ((d & 1) * 16)) & 0xFFFFu);
        int pos = off[d] + (int)hb[d] + rank;
        spair[pos] = make_int2(ei[e], __float_as_int(ewt[e]));
    }
}

// ---------------- fused layer: MFMA-everything (round-15 verified) ---------

template <int CIN, bool DECODE>
__global__ __launch_bounds__(512, 4) void fused_layer(
    const _Float16* __restrict__ xin16, const int* __restrict__ spair,
    const int* __restrict__ off, const float* __restrict__ invc,
    const float* __restrict__ w1, const float* __restrict__ b1,
    const _Float16* __restrict__ Wt, const float* __restrict__ bias,
    void* __restrict__ outp, const float* __restrict__ dw,
    const float* __restrict__ db) {
    constexpr int K = 34 * CIN;              // 544 or 1088
    constexpr int LDK = K + 4;
    constexpr int steps = K / 32;            // 17 or 34
    constexpr int CAP = 192;                 // staged edges per chunk
    constexpr int RPG = 128 / CIN;           // rows per gather instr: 8 or 4
    constexpr int LPR = CIN / 2;             // lanes per row
    constexpr int NIH = CIN / 16;            // i-halves: 1 or 2

    extern __shared__ char smem[];
    _Float16* Fl = (_Float16*)smem;                       // 16*LDK f16
    char* poolb = smem + (size_t)16 * LDK * 2;
    int* Ps = (int*)poolb;                                // [2*CAP+64] pairs
    _Float16* Xs = (_Float16*)(poolb + (2 * CAP + 64) * 4); // [CAP*CIN]
    _Float16* Hs = Xs + CAP * CIN;                        // [CAP*32]
    float* red = (float*)poolb;                           // phase-B alias

    const int t = threadIdx.x;
    const int n0 = blockIdx.x * 16;
    const int lane = t & 63, w = t >> 6;     // 8 waves
    const int col = lane & 15, g4 = (lane >> 4) * 4;
    const int qcl = col & 1, qhi = col >> 1;

    const int E0 = off[n0], E1 = off[n0 + 16];
    const int L = E1 - E0;

    const int d0 = n0 + w * 2;
    const int e0l0 = off[d0] - E0;
    const int e1l0 = off[d0 + 1] - E0;
    const int e1l1 = off[d0 + 2] - E0;

    const float w1v = w1[t & 31];
    const float b1v = b1[t & 31];

    f32x4 aS[2][2][NIH];
    f32x4 a0[2][NIH];
    #pragma unroll
    for (int c = 0; c < 2; ++c) {
        #pragma unroll
        for (int mh = 0; mh < 2; ++mh)
            #pragma unroll
            for (int ih = 0; ih < NIH; ++ih) aS[c][mh][ih] = (f32x4){0.f, 0.f, 0.f, 0.f};
        #pragma unroll
        for (int ih = 0; ih < NIH; ++ih) a0[c][ih] = (f32x4){0.f, 0.f, 0.f, 0.f};
    }

    for (int base = 0; base < L; base += CAP) {
        const int Lc = (L - base < CAP) ? (L - base) : CAP;

        // ---- A1: stage (src, ew) pairs ----
        for (int c = w * 64; c < 2 * Lc; c += 512) {
            int gidx = 2 * (E0 + base) + c + lane;
            gidx = (gidx < 2 * EE) ? gidx : (2 * EE - 1);
            gload_lds_b32(spair + gidx, Ps + c);
        }
        __syncthreads();

        // ---- A2: async fp16 row gathers (source pre-swizzled for CIN=32) ----
        {
            const int G = (Lc + RPG - 1) / RPG;
            const int er = lane / LPR, ecp = lane % LPR;
            for (int p = w; p < G; p += 8) {
                int el = p * RPG + er; el = (el < Lc - 1) ? el : (Lc - 1);
                int sn = Ps[2 * el];
                int sp = (CIN == 32) ? (ecp ^ swz4(el)) : ecp;
                gload_lds_b32(xin16 + (size_t)sn * CIN + 2 * sp,
                              Xs + (size_t)p * RPG * CIN);
            }
        }
        // ---- H build (swizzled store; m = t&31 fixed) ----
        for (int idx = t; idx < Lc * 32; idx += 512) {
            int e = idx >> 5, m = idx & 31;
            float ew = __int_as_float(Ps[2 * e + 1]);
            int slot = (((m >> 1) ^ swz4(e)) << 1) + (m & 1);
            Hs[e * 32 + slot] = (_Float16)silu_f(fmaf(ew, w1v, b1v));
        }
        __syncthreads();

        // ---- A3: per-node MFMA aggregation ----
        #pragma unroll
        for (int c = 0; c < 2; ++c) {
            int lo = ((c == 0) ? e0l0 : e1l0) - base;
            int hi = ((c == 0) ? e1l0 : e1l1) - base;
            lo = (lo < 0) ? 0 : lo;
            hi = (hi > Lc) ? Lc : hi;
            for (int ks = lo; ks < hi; ks += 32) {
                f16x8 bf[NIH];
                #pragma unroll
                for (int ih = 0; ih < NIH; ++ih) {
                    const int qx = ih * 8 + qhi;
                    #pragma unroll
                    for (int j = 0; j < 4; ++j) {
                        int k1 = ks + g4 + j, k2 = k1 + 16;
                        int c1 = (k1 < hi) ? k1 : (Lc - 1);
                        int c2 = (k2 < hi) ? k2 : (Lc - 1);
                        if (CIN == 32) {
                            bf[ih][j]     = Xs[c1 * 32 + ((qx ^ swz4(c1)) << 1) + qcl];
                            bf[ih][j + 4] = Xs[c2 * 32 + ((qx ^ swz4(c2)) << 1) + qcl];
                        } else {
                            bf[ih][j]     = Xs[c1 * CIN + ih * 16 + col];
                            bf[ih][j + 4] = Xs[c2 * CIN + ih * 16 + col];
                        }
                    }
                }
                f16x8 af[2];
                #pragma unroll
                for (int mh = 0; mh < 2; ++mh) {
                    const int qh = mh * 8 + qhi;
                    #pragma unroll
                    for (int j = 0; j < 4; ++j) {
                        int k1 = ks + g4 + j, k2 = k1 + 16;
                        int c1 = (k1 < hi) ? k1 : (Lc - 1);
                        int c2 = (k2 < hi) ? k2 : (Lc - 1);
                        _Float16 v1 = Hs[c1 * 32 + ((qh ^ swz4(c1)) << 1) + qcl];
                        _Float16 v2 = Hs[c2 * 32 + ((qh ^ swz4(c2)) << 1) + qcl];
                        af[mh][j]     = (k1 < hi) ? v1 : (_Float16)0;
                        af[mh][j + 4] = (k2 < hi) ? v2 : (_Float16)0;
                    }
                }
                f16x8 ao;
                #pragma unroll
                for (int j = 0; j < 4; ++j) {
                    int k1 = ks + g4 + j, k2 = k1 + 16;
                    ao[j]     = (col == 0 && k1 < hi) ? (_Float16)1 : (_Float16)0;
                    ao[j + 4] = (col == 0 && k2 < hi) ? (_Float16)1 : (_Float16)0;
                }
                #pragma unroll
                for (int mh = 0; mh < 2; ++mh)
                    #pragma unroll
                    for (int ih = 0; ih < NIH; ++ih)
                        aS[c][mh][ih] = __builtin_amdgcn_mfma_f32_16x16x32_f16(
                            af[mh], bf[ih], aS[c][mh][ih], 0, 0, 0);
                #pragma unroll
                for (int ih = 0; ih < NIH; ++ih)
                    a0[c][ih] = __builtin_amdgcn_mfma_f32_16x16x32_f16(
                        ao, bf[ih], a0[c][ih], 0, 0, 0);
            }
        }
        if (base + CAP < L) __syncthreads();
    }

    // ---- tail: write F rows ----
    #pragma unroll
    for (int c = 0; c < 2; ++c) {
        const int d = n0 + w * 2 + c;
        const float iv = invc[d];
        _Float16* Fr = Fl + (size_t)(w * 2 + c) * LDK;
        #pragma unroll
        for (int mh = 0; mh < 2; ++mh)
            #pragma unroll
            for (int ih = 0; ih < NIH; ++ih)
                #pragma unroll
                for (int r = 0; r < 4; ++r)
                    Fr[32 * (ih * 16 + col) + mh * 16 + g4 + r] =
                        (_Float16)(aS[c][mh][ih][r] * iv);
        if (g4 == 0) {
            #pragma unroll
            for (int ih = 0; ih < NIH; ++ih)
                Fr[32 * CIN + ih * 16 + col] = (_Float16)(a0[c][ih][0] * iv);
        }
        if (lane >= CIN && lane < 2 * CIN)
            Fr[32 * CIN + lane] = xin16[(size_t)d * CIN + (lane - CIN)];
    }
    __syncthreads();

    // ---- Phase B: 8-way K-split MFMA (verified) ----
    const int o16 = col, g = lane >> 4;

    const _Float16* Arow = Fl + (size_t)o16 * LDK + g * 4;
    const _Float16* B0 = Wt + (size_t)o16 * K + g * 4;
    const _Float16* B1 = Wt + (size_t)(o16 + 16) * K + g * 4;

    f32x4 acc0 = {0.f, 0.f, 0.f, 0.f};
    f32x4 acc1 = {0.f, 0.f, 0.f, 0.f};

    const int sb = (steps * w) >> 3;
    const int se = (steps * (w + 1)) >> 3;
    #pragma unroll 2
    for (int s = sb; s < se; ++s) {
        const int k0 = s * 32;
        f16x4 alo = *(const f16x4*)(Arow + k0);
        f16x4 ahi = *(const f16x4*)(Arow + k0 + 16);
        f16x4 b0l = *(const f16x4*)(B0 + k0);
        f16x4 b0h = *(const f16x4*)(B0 + k0 + 16);
        f16x4 b1l = *(const f16x4*)(B1 + k0);
        f16x4 b1h = *(const f16x4*)(B1 + k0 + 16);
        f16x8 a, bb0, bb1;
        #pragma unroll
        for (int j = 0; j < 4; ++j) {
            a[j] = alo[j];  a[j + 4] = ahi[j];
            bb0[j] = b0l[j]; bb0[j + 4] = b0h[j];
            bb1[j] = b1l[j]; bb1[j + 4] = b1h[j];
        }
        acc0 = __builtin_amdgcn_mfma_f32_16x16x32_f16(a, bb0, acc0, 0, 0, 0);
        acc1 = __builtin_amdgcn_mfma_f32_16x16x32_f16(a, bb1, acc1, 0, 0, 0);
    }

    if (w > 0) {
        float* rw = red + (w - 1) * 512;
        #pragma unroll
        for (int r = 0; r < 4; ++r) {
            rw[(g * 4 + r) * 32 + o16]      = acc0[r];
            rw[(g * 4 + r) * 32 + 16 + o16] = acc1[r];
        }
    }
    __syncthreads();
    if (w == 0) {
        #pragma unroll
        for (int r = 0; r < 4; ++r) {
            const int ro = (g * 4 + r) * 32 + o16;
            #pragma unroll
            for (int p = 0; p < 7; ++p) {
                acc0[r] += red[p * 512 + ro];
                acc1[r] += red[p * 512 + ro + 16];
            }
        }
        const float bb0 = bias[o16], bb1 = bias[o16 + 16];
        const int nrow = n0 + g * 4;
        if (!DECODE) {
            _Float16* op = (_Float16*)outp;
            #pragma unroll
            for (int r = 0; r < 4; ++r) {
                op[(size_t)(nrow + r) * 32 + o16]      = (_Float16)silu_f(acc0[r] + bb0);
                op[(size_t)(nrow + r) * 32 + 16 + o16] = (_Float16)silu_f(acc1[r] + bb1);
            }
        } else {
            float* op = (float*)outp;
            const float w0 = dw[o16], w1vv = dw[o16 + 16];
            const float dbv = db[0];
            #pragma unroll
            for (int r = 0; r < 4; ++r) {
                float p = silu_f(acc0[r] + bb0) * w0 + silu_f(acc1[r] + bb1) * w1vv;
                p += __shfl_xor(p, 1);
                p += __shfl_xor(p, 2);
                p += __shfl_xor(p, 4);
                p += __shfl_xor(p, 8);
                if (o16 == 0) op[nrow + r] = p + dbv;
            }
        }
    }
}

// ---------------- launch ----------------

extern "C" void kernel_launch(void* const* d_in, const int* in_sizes, int n_in,
                              void* d_out, int out_size, void* d_ws, size_t ws_size,
                              hipStream_t stream) {
    const float* x      = (const float*)d_in[0];
    const int*   ei     = (const int*)d_in[1];
    const float* ew     = (const float*)d_in[2];
    const float* en1_w1 = (const float*)d_in[3];
    const float* en1_b1 = (const float*)d_in[4];
    const float* en1_w2 = (const float*)d_in[5];
    const float* en1_b2 = (const float*)d_in[6];
    const float* root1  = (const float*)d_in[7];
    const float* bias1  = (const float*)d_in[8];
    const float* en2_w1 = (const float*)d_in[9];
    const float* en2_b1 = (const float*)d_in[10];
    const float* en2_w2 = (const float*)d_in[11];
    const float* en2_b2 = (const float*)d_in[12];
    const float* root2  = (const float*)d_in[13];
    const float* bias2  = (const float*)d_in[14];
    const float* dec_w  = (const float*)d_in[15];
    const float* dec_b  = (const float*)d_in[16];
    float* out = (float*)d_out;
    (void)in_sizes; (void)n_in; (void)out_size; (void)ws_size;

    char* wp = (char*)d_ws;
    auto alloc = [&](size_t bytes) {
        char* p = wp;
        wp += (bytes + 255) & ~(size_t)255;
        return p;
    };
    unsigned int* histG = (unsigned int*)alloc((size_t)NB * NN * 4);  // 5.12 MB
    int*      cnt   = (int*)alloc((size_t)NN * 4);
    int*      off   = (int*)alloc((size_t)(NN + 1) * 4);
    float*    invc  = (float*)alloc((size_t)NN * 4);
    int2*     spair = (int2*)alloc((size_t)EE * 8);
    _Float16* h1h   = (_Float16*)alloc((size_t)NN * 32 * 2);
    _Float16* x16   = (_Float16*)alloc((size_t)NN * 16 * 2);
    _Float16* Wt1   = (_Float16*)alloc((size_t)17408 * 2);
    _Float16* Wt2   = (_Float16*)alloc((size_t)34816 * 2);
    int*      flag  = (int*)alloc(256);

    const int build_blocks = (52224 + NN * 16 + 255) / 256;   // 1454
    prep_kernel<<<NB + build_blocks, 256, 0, stream>>>(
        ei, en1_w2, en1_b2, root1, en2_w2, en2_b2, root2, x,
        histG, Wt1, Wt2, x16, flag);
    colscan_scan_kernel<<<(NN + 255) / 256, 256, 0, stream>>>(
        histG, cnt, invc, off, flag);
    scatter2_kernel<<<NB, 256, 0, stream>>>(ei, ew, off, histG, spair);

    auto f1 = fused_layer<16, false>;
    auto f2 = fused_layer<32, true>;
    (void)hipFuncSetAttribute((const void*)f1,
                              hipFuncAttributeMaxDynamicSharedMemorySize, 163840);
    (void)hipFuncSetAttribute((const void*)f2,
                              hipFuncAttributeMaxDynamicSharedMemorySize, 163840);

    const size_t lds1 = (size_t)16 * (34 * 16 + 4) * 2 + (448 * 4 + 192 * 16 * 2 + 192 * 64); // 37,760
    const size_t lds2 = (size_t)16 * (34 * 32 + 4) * 2 + (448 * 4 + 192 * 32 * 2 + 192 * 64); // 61,312

    fused_layer<16, false><<<NN / 16, 512, lds1, stream>>>(
        x16, (const int*)spair, off, invc, en1_w1, en1_b1, Wt1, bias1, h1h,
        nullptr, nullptr);
    fused_layer<32, true><<<NN / 16, 512, lds2, stream>>>(
        h1h, (const int*)spair, off, invc, en2_w1, en2_b1, Wt2, bias2, out,
        dec_w, dec_b);
}

// Round 17
// 97.418 us; speedup vs baseline: 1.0748x; 1.0748x over previous
//
#include <hip/hip_runtime.h>
#include <hip/hip_bf16.h>

#define NN 20000
#define EE 160000
#define HH 32
#define MIDD 32
#define NB 128
#define EPB 1250   // EE / NB exactly

typedef _Float16 f16x4 __attribute__((ext_vector_type(4)));
typedef _Float16 f16x8 __attribute__((ext_vector_type(8)));
typedef float f32x4 __attribute__((ext_vector_type(4)));

__device__ __forceinline__ float silu_f(float v) {
    return __fdividef(v, 1.0f + __expf(-v));
}

// async global->LDS, 4B per lane; LDS dest = wave-uniform base + 4*lane.
__device__ __forceinline__ void gload_lds_b32(const void* gsrc, void* ldst) {
    __builtin_amdgcn_global_load_lds(
        (const __attribute__((address_space(1))) void*)gsrc,
        (__attribute__((address_space(3))) void*)ldst, 4, 0, 0);
}

// ---------------- prep: per-block LDS histogram + Wt build + x16 cast ------
__global__ __launch_bounds__(256) void prep_kernel(
    const int* __restrict__ ei,
    const float* __restrict__ w2a, const float* __restrict__ b2a,
    const float* __restrict__ ra,
    const float* __restrict__ w2b, const float* __restrict__ b2b,
    const float* __restrict__ rb,
    const float* __restrict__ x,
    unsigned int* __restrict__ histG,
    _Float16* __restrict__ Wt1, _Float16* __restrict__ Wt2,
    _Float16* __restrict__ x16) {
    const int t = threadIdx.x;
    if (blockIdx.x < NB) {
        __shared__ unsigned int h2[NN / 2];
        for (int i = t; i < NN / 2; i += 256) h2[i] = 0u;
        __syncthreads();
        const int base = blockIdx.x * EPB;
        for (int e = base + t; e < base + EPB; e += 256) {
            int d = ei[EE + e];
            atomicAdd(&h2[d >> 1], 1u << ((d & 1) * 16));
        }
        __syncthreads();
        unsigned int* outp = histG + (size_t)blockIdx.x * NN;
        for (int n = t; n < NN; n += 256)
            outp[n] = (h2[n >> 1] >> ((n & 1) * 16)) & 0xFFFFu;
        return;
    }
    int idx = (blockIdx.x - NB) * 256 + t;
    if (idx < 17408) {                       // 32 * 544 (CIN=16)
        int o = idx / 544, k = idx % 544;
        float v;
        if (k < 512) {
            int m = k & 31, i = k >> 5;
            v = w2a[m * 512 + i * 32 + o];
        } else if (k < 528) {
            v = b2a[(k - 512) * 32 + o];
        } else {
            v = ra[(k - 528) * 32 + o];
        }
        Wt1[o * 544 + k] = (_Float16)v;
    } else if (idx < 52224) {                // + 32 * 1088 (CIN=32)
        int j = idx - 17408;
        int o = j / 1088, k = j % 1088;
        float v;
        if (k < 1024) {
            int m = k & 31, i = k >> 5;
            v = w2b[m * 1024 + i * 32 + o];
        } else if (k < 1056) {
            v = b2b[(k - 1024) * 32 + o];
        } else {
            v = rb[(k - 1056) * 32 + o];
        }
        Wt2[o * 1088 + k] = (_Float16)v;
    } else if (idx < 52224 + NN * 16) {      // x -> fp16
        int j = idx - 52224;
        x16[j] = (_Float16)x[j];
    }
}

// per-node prefix over block histograms (round-13 verified).
__global__ __launch_bounds__(256) void colscan_kernel(
    unsigned int* __restrict__ histG, int* __restrict__ cnt,
    float* __restrict__ invc) {
    const int n = blockIdx.x * 256 + threadIdx.x;
    if (n >= NN) return;
    unsigned int s = 0;
    #pragma unroll 4
    for (int b = 0; b < NB; ++b) {
        unsigned int v = histG[(size_t)b * NN + n];
        histG[(size_t)b * NN + n] = s;
        s += v;
    }
    cnt[n] = (int)s;
    invc[n] = 1.0f / fmaxf((float)s, 1.0f);
}

// Vectorized single-block scan (round-10 verified; off only).
__global__ __launch_bounds__(1024) void scan_kernel(
    const int* __restrict__ cnt, int* __restrict__ off) {
    const int t = threadIdx.x;
    const int base = t * 20;
    __shared__ int wtot[16];

    int c[20];
    if (base + 20 <= NN) {
        const int4* p = (const int4*)(cnt + base);
        #pragma unroll
        for (int q = 0; q < 5; ++q) *(int4*)&c[4 * q] = p[q];
    } else {
        #pragma unroll
        for (int r = 0; r < 20; ++r) {
            int idx = base + r;
            c[r] = (idx < NN) ? cnt[idx] : 0;
        }
    }

    int loc[20];
    int s = 0;
    #pragma unroll
    for (int r = 0; r < 20; ++r) { loc[r] = s; s += c[r]; }

    const int lane = t & 63, wv = t >> 6;
    int incl = s;
    #pragma unroll
    for (int d2 = 1; d2 < 64; d2 <<= 1) {
        int u = __shfl_up(incl, d2);
        if (lane >= d2) incl += u;
    }
    if (lane == 63) wtot[wv] = incl;
    __syncthreads();
    int wbase = 0;
    for (int p2 = 0; p2 < wv; ++p2) wbase += wtot[p2];

    const int excl = wbase + incl - s;

    int o[20];
    #pragma unroll
    for (int r = 0; r < 20; ++r) o[r] = excl + loc[r];

    if (base + 20 <= NN) {
        #pragma unroll
        for (int q = 0; q < 5; ++q)
            ((int4*)(off + base))[q] = *(const int4*)&o[4 * q];
    } else {
        #pragma unroll
        for (int r = 0; r < 20; ++r) {
            int idx = base + r;
            if (idx < NN) off[idx] = o[r];
        }
    }
    if (t == 0) off[NN] = EE;
}

// scatter without global atomics (round-13 verified).
__global__ __launch_bounds__(256) void scatter2_kernel(
    const int* __restrict__ ei, const float* __restrict__ ewt,
    const int* __restrict__ off, const unsigned int* __restrict__ histG,
    int2* __restrict__ spair) {
    __shared__ unsigned int r2[NN / 2];
    const int t = threadIdx.x, b = blockIdx.x;
    for (int i = t; i < NN / 2; i += 256) r2[i] = 0u;
    __syncthreads();
    const int base = b * EPB;
    const unsigned int* hb = histG + (size_t)b * NN;
    for (int e = base + t; e < base + EPB; e += 256) {
        int d = ei[EE + e];
        unsigned int old = atomicAdd(&r2[d >> 1], 1u << ((d & 1) * 16));
        int rank = (int)((old >> ((d & 1) * 16)) & 0xFFFFu);
        int pos = off[d] + (int)hb[d] + rank;
        spair[pos] = make_int2(ei[e], __float_as_int(ewt[e]));
    }
}

// ---------------- fused layer: MFMA-everything (round-13 base) -------------
// Change vs round 13: Xs gets +40 pad rows, Hs +32 pad rows. A2's clamped
// gather loop is extended to fill the pad with duplicates of row Lc-1
// (finite data, no NaN hazard), so A3 reads fragments UNCLAMPED: bf is a
// bare LDS read; af keeps only the k<hi select (mask annihilates pad slots).

template <int CIN, bool DECODE>
__global__ __launch_bounds__(512, 4) void fused_layer(
    const _Float16* __restrict__ xin16, const int* __restrict__ spair,
    const int* __restrict__ off, const float* __restrict__ invc,
    const float* __restrict__ w1, const float* __restrict__ b1,
    const _Float16* __restrict__ Wt, const float* __restrict__ bias,
    void* __restrict__ outp, const float* __restrict__ dw,
    const float* __restrict__ db) {
    constexpr int K = 34 * CIN;              // 544 or 1088
    constexpr int LDK = K + 4;
    constexpr int steps = K / 32;            // 17 or 34
    constexpr int CAP = 192;                 // staged edges per chunk
    constexpr int RPG = 128 / CIN;           // rows per gather instr: 8 or 4
    constexpr int LPR = CIN / 2;             // lanes per row
    constexpr int NIH = CIN / 16;            // i-halves: 1 or 2
    constexpr int XROWS = CAP + 40;          // pad covers gather over-run
    constexpr int HROWS = CAP + 32;          // pad covers unclamped af reads

    extern __shared__ char smem[];
    _Float16* Fl = (_Float16*)smem;                       // 16*LDK f16
    char* poolb = smem + (size_t)16 * LDK * 2;
    int* Ps = (int*)poolb;                                // [2*CAP+64] pairs
    _Float16* Xs = (_Float16*)(poolb + (2 * CAP + 64) * 4); // [XROWS*CIN]
    _Float16* Hs = Xs + XROWS * CIN;                      // [HROWS*32]
    float* red = (float*)poolb;                           // phase-B alias

    const int t = threadIdx.x;
    const int n0 = blockIdx.x * 16;
    const int lane = t & 63, w = t >> 6;     // 8 waves
    const int col = lane & 15, g4 = (lane >> 4) * 4;

    const int E0 = off[n0], E1 = off[n0 + 16];
    const int L = E1 - E0;

    const int d0 = n0 + w * 2;
    const int e0l0 = off[d0] - E0;
    const int e1l0 = off[d0 + 1] - E0;
    const int e1l1 = off[d0 + 2] - E0;

    const float w1v = w1[t & 31];
    const float b1v = b1[t & 31];

    f32x4 aS[2][2][NIH];
    f32x4 a0[2][NIH];
    #pragma unroll
    for (int c = 0; c < 2; ++c) {
        #pragma unroll
        for (int mh = 0; mh < 2; ++mh)
            #pragma unroll
            for (int ih = 0; ih < NIH; ++ih) aS[c][mh][ih] = (f32x4){0.f, 0.f, 0.f, 0.f};
        #pragma unroll
        for (int ih = 0; ih < NIH; ++ih) a0[c][ih] = (f32x4){0.f, 0.f, 0.f, 0.f};
    }

    for (int base = 0; base < L; base += CAP) {
        const int Lc = (L - base < CAP) ? (L - base) : CAP;

        // ---- A1: stage (src, ew) pairs ----
        for (int c = w * 64; c < 2 * Lc; c += 512) {
            int gidx = 2 * (E0 + base) + c + lane;
            gidx = (gidx < 2 * EE) ? gidx : (2 * EE - 1);
            gload_lds_b32(spair + gidx, Ps + c);
        }
        __syncthreads();

        // ---- A2: async fp16 row gathers, extended to fill pad with
        //      duplicates of row Lc-1 (finite -> masked products stay 0) ----
        if (Lc > 0) {
            const int G = (Lc + 32 + RPG - 1) / RPG;   // covers [0, Lc+32)
            const int er = lane / LPR, ecp = lane % LPR;
            for (int p = w; p < G; p += 8) {
                int el = p * RPG + er; el = (el < Lc - 1) ? el : (Lc - 1);
                int sn = Ps[2 * el];
                gload_lds_b32(xin16 + (size_t)sn * CIN + 2 * ecp,
                              Xs + (size_t)p * RPG * CIN);
            }
        }
        // ---- H build (m = t&31 fixed) ----
        for (int idx = t; idx < Lc * 32; idx += 512) {
            int e = idx >> 5;
            float ew = __int_as_float(Ps[2 * e + 1]);
            Hs[idx] = (_Float16)silu_f(fmaf(ew, w1v, b1v));
        }
        __syncthreads();

        // ---- A3: per-node MFMA aggregation (unclamped fragment reads) ----
        #pragma unroll
        for (int c = 0; c < 2; ++c) {
            int lo = ((c == 0) ? e0l0 : e1l0) - base;
            int hi = ((c == 0) ? e1l0 : e1l1) - base;
            lo = (lo < 0) ? 0 : lo;
            hi = (hi > Lc) ? Lc : hi;
            for (int ks = lo; ks < hi; ks += 32) {
                const int k1b = ks + g4;         // lane's low k-slot base
                f16x8 bf[NIH];
                #pragma unroll
                for (int ih = 0; ih < NIH; ++ih)
                    #pragma unroll
                    for (int j = 0; j < 4; ++j) {
                        bf[ih][j]     = Xs[(k1b + j) * CIN + ih * 16 + col];
                        bf[ih][j + 4] = Xs[(k1b + j + 16) * CIN + ih * 16 + col];
                    }
                f16x8 af[2];
                #pragma unroll
                for (int mh = 0; mh < 2; ++mh)
                    #pragma unroll
                    for (int j = 0; j < 4; ++j) {
                        int k1 = k1b + j, k2 = k1 + 16;
                        _Float16 v1 = Hs[k1 * 32 + mh * 16 + col];
                        _Float16 v2 = Hs[k2 * 32 + mh * 16 + col];
                        af[mh][j]     = (k1 < hi) ? v1 : (_Float16)0;
                        af[mh][j + 4] = (k2 < hi) ? v2 : (_Float16)0;
                    }
                f16x8 ao;
                #pragma unroll
                for (int j = 0; j < 4; ++j) {
                    int k1 = k1b + j, k2 = k1 + 16;
                    ao[j]     = (col == 0 && k1 < hi) ? (_Float16)1 : (_Float16)0;
                    ao[j + 4] = (col == 0 && k2 < hi) ? (_Float16)1 : (_Float16)0;
                }
                #pragma unroll
                for (int mh = 0; mh < 2; ++mh)
                    #pragma unroll
                    for (int ih = 0; ih < NIH; ++ih)
                        aS[c][mh][ih] = __builtin_amdgcn_mfma_f32_16x16x32_f16(
                            af[mh], bf[ih], aS[c][mh][ih], 0, 0, 0);
                #pragma unroll
                for (int ih = 0; ih < NIH; ++ih)
                    a0[c][ih] = __builtin_amdgcn_mfma_f32_16x16x32_f16(
                        ao, bf[ih], a0[c][ih], 0, 0, 0);
            }
        }
        if (base + CAP < L) __syncthreads();
    }

    // ---- tail: write F rows ----
    #pragma unroll
    for (int c = 0; c < 2; ++c) {
        const int d = n0 + w * 2 + c;
        const float iv = invc[d];
        _Float16* Fr = Fl + (size_t)(w * 2 + c) * LDK;
        #pragma unroll
        for (int mh = 0; mh < 2; ++mh)
            #pragma unroll
            for (int ih = 0; ih < NIH; ++ih)
                #pragma unroll
                for (int r = 0; r < 4; ++r)
                    Fr[32 * (ih * 16 + col) + mh * 16 + g4 + r] =
                        (_Float16)(aS[c][mh][ih][r] * iv);
        if (g4 == 0) {
            #pragma unroll
            for (int ih = 0; ih < NIH; ++ih)
                Fr[32 * CIN + ih * 16 + col] = (_Float16)(a0[c][ih][0] * iv);
        }
        if (lane >= CIN && lane < 2 * CIN)
            Fr[32 * CIN + lane] = xin16[(size_t)d * CIN + (lane - CIN)];
    }
    __syncthreads();

    // ---- Phase B: 8-way K-split MFMA (verified) ----
    const int o16 = col, g = lane >> 4;

    const _Float16* Arow = Fl + (size_t)o16 * LDK + g * 4;
    const _Float16* B0 = Wt + (size_t)o16 * K + g * 4;
    const _Float16* B1 = Wt + (size_t)(o16 + 16) * K + g * 4;

    f32x4 acc0 = {0.f, 0.f, 0.f, 0.f};
    f32x4 acc1 = {0.f, 0.f, 0.f, 0.f};

    const int sb = (steps * w) >> 3;
    const int se = (steps * (w + 1)) >> 3;
    #pragma unroll 2
    for (int s = sb; s < se; ++s) {
        const int k0 = s * 32;
        f16x4 alo = *(const f16x4*)(Arow + k0);
        f16x4 ahi = *(const f16x4*)(Arow + k0 + 16);
        f16x4 b0l = *(const f16x4*)(B0 + k0);
        f16x4 b0h = *(const f16x4*)(B0 + k0 + 16);
        f16x4 b1l = *(const f16x4*)(B1 + k0);
        f16x4 b1h = *(const f16x4*)(B1 + k0 + 16);
        f16x8 a, bb0, bb1;
        #pragma unroll
        for (int j = 0; j < 4; ++j) {
            a[j] = alo[j];  a[j + 4] = ahi[j];
            bb0[j] = b0l[j]; bb0[j + 4] = b0h[j];
            bb1[j] = b1l[j]; bb1[j + 4] = b1h[j];
        }
        acc0 = __builtin_amdgcn_mfma_f32_16x16x32_f16(a, bb0, acc0, 0, 0, 0);
        acc1 = __builtin_amdgcn_mfma_f32_16x16x32_f16(a, bb1, acc1, 0, 0, 0);
    }

    if (w > 0) {
        float* rw = red + (w - 1) * 512;
        #pragma unroll
        for (int r = 0; r < 4; ++r) {
            rw[(g * 4 + r) * 32 + o16]      = acc0[r];
            rw[(g * 4 + r) * 32 + 16 + o16] = acc1[r];
        }
    }
    __syncthreads();
    if (w == 0) {
        #pragma unroll
        for (int r = 0; r < 4; ++r) {
            const int ro = (g * 4 + r) * 32 + o16;
            #pragma unroll
            for (int p = 0; p < 7; ++p) {
                acc0[r] += red[p * 512 + ro];
                acc1[r] += red[p * 512 + ro + 16];
            }
        }
        const float bb0 = bias[o16], bb1 = bias[o16 + 16];
        const int nrow = n0 + g * 4;
        if (!DECODE) {
            _Float16* op = (_Float16*)outp;
            #pragma unroll
            for (int r = 0; r < 4; ++r) {
                op[(size_t)(nrow + r) * 32 + o16]      = (_Float16)silu_f(acc0[r] + bb0);
                op[(size_t)(nrow + r) * 32 + 16 + o16] = (_Float16)silu_f(acc1[r] + bb1);
            }
        } else {
            float* op = (float*)outp;
            const float w0 = dw[o16], w1vv = dw[o16 + 16];
            const float dbv = db[0];
            #pragma unroll
            for (int r = 0; r < 4; ++r) {
                float p = silu_f(acc0[r] + bb0) * w0 + silu_f(acc1[r] + bb1) * w1vv;
                p += __shfl_xor(p, 1);
                p += __shfl_xor(p, 2);
                p += __shfl_xor(p, 4);
                p += __shfl_xor(p, 8);
                if (o16 == 0) op[nrow + r] = p + dbv;
            }
        }
    }
}

// ---------------- launch ----------------

extern "C" void kernel_launch(void* const* d_in, const int* in_sizes, int n_in,
                              void* d_out, int out_size, void* d_ws, size_t ws_size,
                              hipStream_t stream) {
    const float* x      = (const float*)d_in[0];
    const int*   ei     = (const int*)d_in[1];
    const float* ew     = (const float*)d_in[2];
    const float* en1_w1 = (const float*)d_in[3];
    const float* en1_b1 = (const float*)d_in[4];
    const float* en1_w2 = (const float*)d_in[5];
    const float* en1_b2 = (const float*)d_in[6];
    const float* root1  = (const float*)d_in[7];
    const float* bias1  = (const float*)d_in[8];
    const float* en2_w1 = (const float*)d_in[9];
    const float* en2_b1 = (const float*)d_in[10];
    const float* en2_w2 = (const float*)d_in[11];
    const float* en2_b2 = (const float*)d_in[12];
    const float* root2  = (const float*)d_in[13];
    const float* bias2  = (const float*)d_in[14];
    const float* dec_w  = (const float*)d_in[15];
    const float* dec_b  = (const float*)d_in[16];
    float* out = (float*)d_out;
    (void)in_sizes; (void)n_in; (void)out_size; (void)ws_size;

    char* wp = (char*)d_ws;
    auto alloc = [&](size_t bytes) {
        char* p = wp;
        wp += (bytes + 255) & ~(size_t)255;
        return p;
    };
    unsigned int* histG = (unsigned int*)alloc((size_t)NB * NN * 4);  // 10.24 MB
    int*      cnt   = (int*)alloc((size_t)NN * 4);
    int*      off   = (int*)alloc((size_t)(NN + 1) * 4);
    float*    invc  = (float*)alloc((size_t)NN * 4);
    int2*     spair = (int2*)alloc((size_t)EE * 8);
    _Float16* h1h   = (_Float16*)alloc((size_t)NN * 32 * 2);
    _Float16* x16   = (_Float16*)alloc((size_t)NN * 16 * 2);
    _Float16* Wt1   = (_Float16*)alloc((size_t)17408 * 2);
    _Float16* Wt2   = (_Float16*)alloc((size_t)34816 * 2);

    const int build_blocks = (52224 + NN * 16 + 255) / 256;   // 1454
    prep_kernel<<<NB + build_blocks, 256, 0, stream>>>(
        ei, en1_w2, en1_b2, root1, en2_w2, en2_b2, root2, x,
        histG, Wt1, Wt2, x16);
    colscan_kernel<<<(NN + 255) / 256, 256, 0, stream>>>(histG, cnt, invc);
    scan_kernel<<<1, 1024, 0, stream>>>(cnt, off);
    scatter2_kernel<<<NB, 256, 0, stream>>>(ei, ew, off, histG, spair);

    auto f1 = fused_layer<16, false>;
    auto f2 = fused_layer<32, true>;
    (void)hipFuncSetAttribute((const void*)f1,
                              hipFuncAttributeMaxDynamicSharedMemorySize, 163840);
    (void)hipFuncSetAttribute((const void*)f2,
                              hipFuncAttributeMaxDynamicSharedMemorySize, 163840);

    // lds = Fl + Ps + Xs(CAP+40 rows) + Hs(CAP+32 rows); red (14336B) aliases
    const size_t lds1 = (size_t)16 * (34 * 16 + 4) * 2 + 448 * 4
                      + (size_t)(192 + 40) * 16 * 2 + (size_t)(192 + 32) * 32 * 2; // 41,088
    const size_t lds2 = (size_t)16 * (34 * 32 + 4) * 2 + 448 * 4
                      + (size_t)(192 + 40) * 32 * 2 + (size_t)(192 + 32) * 32 * 2; // 65,920

    fused_layer<16, false><<<NN / 16, 512, lds1, stream>>>(
        x16, (const int*)spair, off, invc, en1_w1, en1_b1, Wt1, bias1, h1h,
        nullptr, nullptr);
    fused_layer<32, true><<<NN / 16, 512, lds2, stream>>>(
        h1h, (const int*)spair, off, invc, en2_w1, en2_b1, Wt2, bias2, out,
        dec_w, dec_b);
}